// Round 4
// baseline (61.688 us; speedup 1.0000x reference)
//
#include <hip/hip_runtime.h>
#include <math.h>

#define D 256
#define TWOD 512
#define BB 1024
#define NN 131072
#define LOG2E 1.4426950408889634f

typedef float v4f __attribute__((ext_vector_type(4)));

__device__ __forceinline__ v4f ldg_nt(const float* p, bool valid) {
  v4f z = {0.f, 0.f, 0.f, 0.f};
  if (valid) z = __builtin_nontemporal_load((const v4f*)p);
  return z;
}

// ---------------- pre: LDS-tiled transposes + segment offsets
__global__ __launch_bounds__(256) void pre_kernel(
    const float* __restrict__ Wq, const float* __restrict__ Wv,
    const float* __restrict__ Wo, const int* __restrict__ bidx,
    float* __restrict__ WqT, float* __restrict__ WvT,
    float* __restrict__ WoT, int* __restrict__ offs) {
  const int blk = blockIdx.x;
  const int t = threadIdx.x;
  if (blk < 64) {
    __shared__ float tile[64][65];
    const float* src; float* dst; int r0, c0, C;
    if (blk < 16)      { src = Wq; dst = WqT; C = 256; r0 = (blk >> 2) * 64;        c0 = (blk & 3) * 64; }
    else if (blk < 32) { int b = blk - 16; src = Wv; dst = WvT; C = 256; r0 = (b >> 2) * 64; c0 = (b & 3) * 64; }
    else               { int b = blk - 32; src = Wo; dst = WoT; C = 512; r0 = (b >> 3) * 64; c0 = (b & 7) * 64; }
    const int lane = t & 63, sr = t >> 6;
    #pragma unroll 4
    for (int rr = 0; rr < 16; ++rr) {
      const int r = rr * 4 + sr;
      tile[r][lane] = src[(size_t)(r0 + r) * C + c0 + lane];
    }
    __syncthreads();
    #pragma unroll 4
    for (int rr = 0; rr < 16; ++rr) {
      const int r = rr * 4 + sr;
      dst[(size_t)(c0 + r) * 256 + r0 + lane] = tile[lane][r];
    }
  } else {
    const int i = (blk - 64) * 256 + t;
    if (i > BB) return;
    int lo = 0, hi = NN;
    while (lo < hi) {
      const int mid = (lo + hi) >> 1;
      if (bidx[mid] < i) lo = mid + 1; else hi = mid;
    }
    offs[i] = lo;
  }
}

// ---------------- kq: q1 = Wq V + bq ; qt = Wk^T q1
// 128 blocks x 512 threads (8 waves), 8 batches per block.
__global__ __launch_bounds__(512) void kq_kernel(
    const float* __restrict__ V, const float* __restrict__ WqT,
    const float* __restrict__ Wk, const float* __restrict__ bq,
    float* __restrict__ qt) {
  __shared__ __align__(16) float part[4][8][D];   // 32 KB
  __shared__ __align__(16) float q1s[D][8];       // 8 KB
  __shared__ __align__(16) float Vs[D][8];        // 8 KB
  const int t = threadIdx.x;
  const int wq = __builtin_amdgcn_readfirstlane(t >> 6);
  const int lane = t & 63;
  const int k4 = lane * 4;
  const int b0 = blockIdx.x * 8;

  // stage V -> Vs[d][i]
  {
    const int d = t & 255, i0 = (t >> 8) * 4;
    #pragma unroll
    for (int j = 0; j < 4; ++j)
      Vs[d][i0 + j] = V[(size_t)(b0 + i0 + j) * D + d];
  }
  __syncthreads();

  v4f a[8];
  // ---- phase A: q1 partials, wave wq covers d in [wq*32,+32)
  #pragma unroll
  for (int i = 0; i < 8; ++i) a[i] = (v4f){0.f, 0.f, 0.f, 0.f};
  {
    const int dbase = wq * 32;
    for (int dd = 0; dd < 32; ++dd) {
      const int d = dbase + dd;
      const v4f w4 = *(const v4f*)(WqT + (size_t)d * D + k4);
      const v4f vlo = *(const v4f*)&Vs[d][0];
      const v4f vhi = *(const v4f*)&Vs[d][4];
      a[0] += w4 * vlo.x; a[1] += w4 * vlo.y; a[2] += w4 * vlo.z; a[3] += w4 * vlo.w;
      a[4] += w4 * vhi.x; a[5] += w4 * vhi.y; a[6] += w4 * vhi.z; a[7] += w4 * vhi.w;
    }
  }
  // two-step cross-wave reduce
  if (wq >= 4) {
    #pragma unroll
    for (int i = 0; i < 8; ++i) *(v4f*)&part[wq - 4][i][k4] = a[i];
  }
  __syncthreads();
  if (wq < 4) {
    #pragma unroll
    for (int i = 0; i < 8; ++i) {
      const v4f p = *(const v4f*)&part[wq][i][k4];
      *(v4f*)&part[wq][i][k4] = a[i] + p;
    }
  }
  __syncthreads();
  {
    const int k = t & 255, i0 = (t >> 8) * 4;
    #pragma unroll
    for (int j = 0; j < 4; ++j) {
      const int i = i0 + j;
      float s = bq[k];
      #pragma unroll
      for (int w = 0; w < 4; ++w) s += part[w][i][k];
      q1s[k][i] = s;
    }
  }
  __syncthreads();

  // ---- phase B: qt partials, wave wq covers k in [wq*32,+32)
  #pragma unroll
  for (int i = 0; i < 8; ++i) a[i] = (v4f){0.f, 0.f, 0.f, 0.f};
  {
    const int kbase = wq * 32;
    for (int kk = 0; kk < 32; ++kk) {
      const int k = kbase + kk;
      const v4f w4 = *(const v4f*)(Wk + (size_t)k * D + k4);
      const v4f qlo = *(const v4f*)&q1s[k][0];
      const v4f qhi = *(const v4f*)&q1s[k][4];
      a[0] += w4 * qlo.x; a[1] += w4 * qlo.y; a[2] += w4 * qlo.z; a[3] += w4 * qlo.w;
      a[4] += w4 * qhi.x; a[5] += w4 * qhi.y; a[6] += w4 * qhi.z; a[7] += w4 * qhi.w;
    }
  }
  if (wq >= 4) {
    #pragma unroll
    for (int i = 0; i < 8; ++i) *(v4f*)&part[wq - 4][i][k4] = a[i];
  }
  __syncthreads();
  if (wq < 4) {
    #pragma unroll
    for (int i = 0; i < 8; ++i) {
      const v4f p = *(const v4f*)&part[wq][i][k4];
      *(v4f*)&part[wq][i][k4] = a[i] + p;
    }
  }
  __syncthreads();
  {
    const int h = t & 255, i0 = (t >> 8) * 4;
    #pragma unroll
    for (int j = 0; j < 4; ++j) {
      const int i = i0 + j;
      float s = 0.f;
      #pragma unroll
      for (int w = 0; w < 4; ++w) s += part[w][i][h];
      qt[(size_t)(b0 + i) * D + h] = s;
    }
  }
}

// ---------------- k1: flash pass, 2 blocks/batch, rotated-rows butterfly (4 rows/wave/iter)
__global__ __launch_bounds__(256) void k1_kernel(
    const float* __restrict__ H, const float* __restrict__ qt,
    const int* __restrict__ offs,
    float* __restrict__ sP, float* __restrict__ mP, float* __restrict__ dP) {
  const int blk = blockIdx.x;
  const int b = blk >> 1, half = blk & 1;
  const int t = threadIdx.x, wave = t >> 6, lane = t & 63;
  const int start = offs[b], end = offs[b + 1];
  const int cnt = end - start;
  const int mid = start + ((cnt + 1) >> 1);
  const int s0 = half ? mid : start;
  const int e0 = half ? end : mid;
  if (s0 >= e0) {
    sP[(size_t)blk * D + t] = 0.f;
    if (t == 0) { mP[blk] = -1e30f; dP[blk] = 0.f; }
    return;
  }
  const v4f q4 = *(const v4f*)(qt + (size_t)b * D + lane * 4);
  const float SC = 0.0625f * LOG2E;
  const int colf = lane * 4;
  const int rot = (lane >> 2) & 3;

  float m = -1e30f, den = 0.f;
  v4f acc = {0.f, 0.f, 0.f, 0.f};

  int n = s0 + wave * 4;
  v4f c0 = ldg_nt(H + (size_t)(n + (rot ^ 0)) * D + colf, n + (rot ^ 0) < e0);
  v4f c1 = ldg_nt(H + (size_t)(n + (rot ^ 1)) * D + colf, n + (rot ^ 1) < e0);
  v4f c2 = ldg_nt(H + (size_t)(n + (rot ^ 2)) * D + colf, n + (rot ^ 2) < e0);
  v4f c3 = ldg_nt(H + (size_t)(n + (rot ^ 3)) * D + colf, n + (rot ^ 3) < e0);
  while (n < e0) {
    const int nn = n + 16;
    v4f p0 = ldg_nt(H + (size_t)(nn + (rot ^ 0)) * D + colf, nn + (rot ^ 0) < e0);
    v4f p1 = ldg_nt(H + (size_t)(nn + (rot ^ 1)) * D + colf, nn + (rot ^ 1) < e0);
    v4f p2 = ldg_nt(H + (size_t)(nn + (rot ^ 2)) * D + colf, nn + (rot ^ 2) < e0);
    v4f p3 = ldg_nt(H + (size_t)(nn + (rot ^ 3)) * D + colf, nn + (rot ^ 3) < e0);

    // per-lane partial dots (chunk = lane, row = n + (rot^j))
    float d0 = c0.x * q4.x; d0 = fmaf(c0.y, q4.y, d0); d0 = fmaf(c0.z, q4.z, d0); d0 = fmaf(c0.w, q4.w, d0);
    float d1 = c1.x * q4.x; d1 = fmaf(c1.y, q4.y, d1); d1 = fmaf(c1.z, q4.z, d1); d1 = fmaf(c1.w, q4.w, d1);
    float d2 = c2.x * q4.x; d2 = fmaf(c2.y, q4.y, d2); d2 = fmaf(c2.z, q4.z, d2); d2 = fmaf(c2.w, q4.w, d2);
    float d3 = c3.x * q4.x; d3 = fmaf(c3.y, q4.y, d3); d3 = fmaf(c3.z, q4.z, d3); d3 = fmaf(c3.w, q4.w, d3);

    // butterfly: pack 4 rows (bits 2,3) then reduce chunks (bits 0,1,4,5)
    const float a01 = d0 + __shfl_xor(d1, 4);
    const float a23 = d2 + __shfl_xor(d3, 4);
    float s4 = a01 + __shfl_xor(a23, 8);
    s4 += __shfl_xor(s4, 1);
    s4 += __shfl_xor(s4, 2);
    s4 += __shfl_xor(s4, 16);
    s4 += __shfl_xor(s4, 32);
    // s4 = full dot of row n+rot (identical across lanes with same rot)
    float sc = s4 * SC;
    if (n + rot >= e0) sc = -1e30f;

    float mm = fmaxf(sc, __shfl_xor(sc, 4));
    mm = fmaxf(mm, __shfl_xor(mm, 8));
    const float nm = fmaxf(m, mm);
    const float f = exp2f(m - nm);
    const float w = exp2f(sc - nm);          // weight for row n+rot
    float ws = w + __shfl_xor(w, 4);
    ws += __shfl_xor(ws, 8);
    den = fmaf(den, f, ws);
    const float w1 = __shfl_xor(w, 4);       // row n+(rot^1)
    const float w2 = __shfl_xor(w, 8);       // row n+(rot^2)
    const float w3 = __shfl_xor(w, 12);      // row n+(rot^3)
    acc = acc * f + c0 * w + c1 * w1 + c2 * w2 + c3 * w3;
    m = nm;

    c0 = p0; c1 = p1; c2 = p2; c3 = p3; n = nn;
  }

  __shared__ float sm[4], sd[4];
  __shared__ __align__(16) float ss[4][D];
  *(v4f*)&ss[wave][lane * 4] = acc;
  if (lane == 0) { sm[wave] = m; sd[wave] = den; }
  __syncthreads();

  const float M = fmaxf(fmaxf(sm[0], sm[1]), fmaxf(sm[2], sm[3]));
  float Dn = 0.f, val = 0.f;
  #pragma unroll
  for (int w2v = 0; w2v < 4; ++w2v) {
    const float f = exp2f(sm[w2v] - M);
    Dn = fmaf(sd[w2v], f, Dn);
    val = fmaf(ss[w2v][t], f, val);
  }
  sP[(size_t)blk * D + t] = val;
  if (t == 0) { mP[blk] = M; dP[blk] = Dn; }
}

// ---------------- k2: merge -> sN ; H~ = Wv sN + bv ; out = Wo [V;H~] + bo
// 128 blocks x 512 threads, 8 batches per block.
__global__ __launch_bounds__(512) void k2_kernel(
    const float* __restrict__ V, const float* __restrict__ WvT,
    const float* __restrict__ WoT, const float* __restrict__ bv,
    const float* __restrict__ bo, const float* __restrict__ sP,
    const float* __restrict__ mP, const float* __restrict__ dP,
    const int* __restrict__ offs, float* __restrict__ out) {
  __shared__ __align__(16) float part[4][8][D];   // 32 KB
  __shared__ __align__(16) float sN[D][8];        // 8 KB
  __shared__ __align__(16) float Us[TWOD][8];     // 16 KB
  const int t = threadIdx.x;
  const int wq = __builtin_amdgcn_readfirstlane(t >> 6);
  const int lane = t & 63;
  const int k4 = lane * 4;
  const int b0 = blockIdx.x * 8;

  // ---- phase 0: merge the two k1 halves; stage V
  {
    const int d = t & 255, i0 = (t >> 8) * 4;
    #pragma unroll
    for (int j = 0; j < 4; ++j) {
      const int i = i0 + j;
      const int bb = b0 + i;
      const float m0 = mP[2 * bb], m1 = mP[2 * bb + 1];
      const float d0 = dP[2 * bb], d1 = dP[2 * bb + 1];
      const float M = fmaxf(m0, m1);
      const float f0 = exp2f(m0 - M), f1 = exp2f(m1 - M);
      const float Dn = d0 * f0 + d1 * f1;
      const float inv = (Dn > 0.f) ? (1.f / Dn) : 0.f;
      sN[d][i] = (sP[(size_t)(2 * bb) * D + d] * f0 +
                  sP[(size_t)(2 * bb + 1) * D + d] * f1) * inv;
      Us[d][i] = V[(size_t)bb * D + d];
    }
  }
  __syncthreads();

  v4f a[8];
  // ---- phase A: H~ partials, wave wq covers h in [wq*32,+32)
  #pragma unroll
  for (int i = 0; i < 8; ++i) a[i] = (v4f){0.f, 0.f, 0.f, 0.f};
  {
    const int hbase = wq * 32;
    for (int hh = 0; hh < 32; ++hh) {
      const int h = hbase + hh;
      const v4f w4 = *(const v4f*)(WvT + (size_t)h * D + k4);
      const v4f slo = *(const v4f*)&sN[h][0];
      const v4f shi = *(const v4f*)&sN[h][4];
      a[0] += w4 * slo.x; a[1] += w4 * slo.y; a[2] += w4 * slo.z; a[3] += w4 * slo.w;
      a[4] += w4 * shi.x; a[5] += w4 * shi.y; a[6] += w4 * shi.z; a[7] += w4 * shi.w;
    }
  }
  if (wq >= 4) {
    #pragma unroll
    for (int i = 0; i < 8; ++i) *(v4f*)&part[wq - 4][i][k4] = a[i];
  }
  __syncthreads();
  if (wq < 4) {
    #pragma unroll
    for (int i = 0; i < 8; ++i) {
      const v4f p = *(const v4f*)&part[wq][i][k4];
      *(v4f*)&part[wq][i][k4] = a[i] + p;
    }
  }
  __syncthreads();
  {
    const int d = t & 255, i0 = (t >> 8) * 4;
    #pragma unroll
    for (int j = 0; j < 4; ++j) {
      const int i = i0 + j;
      float s = bv[d];
      #pragma unroll
      for (int w = 0; w < 4; ++w) s += part[w][i][d];
      Us[D + d][i] = s;
    }
  }
  __syncthreads();

  // ---- phase B: out partials, wave wq covers k in [wq*64,+64)
  #pragma unroll
  for (int i = 0; i < 8; ++i) a[i] = (v4f){0.f, 0.f, 0.f, 0.f};
  {
    const int kbase = wq * 64;
    for (int kk = 0; kk < 64; ++kk) {
      const int k = kbase + kk;
      const v4f w4 = *(const v4f*)(WoT + (size_t)k * D + k4);
      const v4f ulo = *(const v4f*)&Us[k][0];
      const v4f uhi = *(const v4f*)&Us[k][4];
      a[0] += w4 * ulo.x; a[1] += w4 * ulo.y; a[2] += w4 * ulo.z; a[3] += w4 * ulo.w;
      a[4] += w4 * uhi.x; a[5] += w4 * uhi.y; a[6] += w4 * uhi.z; a[7] += w4 * uhi.w;
    }
  }
  if (wq >= 4) {
    #pragma unroll
    for (int i = 0; i < 8; ++i) *(v4f*)&part[wq - 4][i][k4] = a[i];
  }
  __syncthreads();
  if (wq < 4) {
    #pragma unroll
    for (int i = 0; i < 8; ++i) {
      const v4f p = *(const v4f*)&part[wq][i][k4];
      *(v4f*)&part[wq][i][k4] = a[i] + p;
    }
  }
  __syncthreads();
  {
    const int d = t & 255, i0 = (t >> 8) * 4;
    #pragma unroll
    for (int j = 0; j < 4; ++j) {
      const int i = i0 + j;
      const int bb = b0 + i;
      float s = bo[d];
      #pragma unroll
      for (int w = 0; w < 4; ++w) s += part[w][i][d];
      const int c = offs[bb + 1] - offs[bb];
      out[(size_t)bb * D + d] = (c > 0) ? s : Us[d][i];
    }
  }
}

extern "C" void kernel_launch(void* const* d_in, const int* in_sizes, int n_in,
                              void* d_out, int out_size, void* d_ws, size_t ws_size,
                              hipStream_t stream) {
  const float* V   = (const float*)d_in[0];
  const float* H   = (const float*)d_in[1];
  const int* bidx  = (const int*)d_in[2];
  const float* Wq  = (const float*)d_in[3];
  const float* bq  = (const float*)d_in[4];
  const float* Wk  = (const float*)d_in[5];
  const float* Wv  = (const float*)d_in[7];
  const float* bv  = (const float*)d_in[8];
  const float* Wo  = (const float*)d_in[9];
  const float* bo  = (const float*)d_in[10];
  float* out = (float*)d_out;

  float* ws  = (float*)d_ws;
  float* WqT = ws;                       // 256*256
  float* WvT = WqT + D * D;              // 256*256
  float* WoT = WvT + D * D;              // 512*256
  float* qt  = WoT + TWOD * D;           // 1024*256
  float* sP  = qt + BB * D;              // 2048*256
  float* mP  = sP + 2 * BB * D;          // 2048
  float* dP  = mP + 2 * BB;              // 2048
  int* offs  = (int*)(dP + 2 * BB);      // 1025

  hipLaunchKernelGGL(pre_kernel, dim3(69), dim3(256), 0, stream,
                     Wq, Wv, Wo, bidx, WqT, WvT, WoT, offs);
  hipLaunchKernelGGL(kq_kernel, dim3(BB / 8), dim3(512), 0, stream,
                     V, WqT, Wk, bq, qt);
  hipLaunchKernelGGL(k1_kernel, dim3(2 * BB), dim3(256), 0, stream,
                     H, qt, offs, sP, mP, dP);
  hipLaunchKernelGGL(k2_kernel, dim3(BB / 8), dim3(512), 0, stream,
                     V, WvT, WoT, bv, bo, sP, mP, dP, offs, out);
}